// Round 14
// baseline (171.511 us; speedup 1.0000x reference)
//
#include <hip/hip_runtime.h>
#include <stdint.h>

#define B_    4096
#define T_    48
#define D_    35
#define TS    40      // stash per-timestep stride (elems)
#define RS    1928    // stash per-row stride (elems)
#define L2E   1.44269504f

typedef float f32x4 __attribute__((ext_vector_type(4)));
typedef short bf16x8 __attribute__((ext_vector_type(8)));
union U4 { uint32_t u[4]; bf16x8 v; };

static __device__ __forceinline__ uint32_t fbits(float x){union{float f;uint32_t u;}v;v.f=x;return v.u;}
static __device__ __forceinline__ float bitsf(uint32_t u){union{uint32_t u;float f;}v;v.u=u;return v.f;}
static __device__ __forceinline__ float bf2f(uint32_t b){return bitsf(b<<16);}
static __device__ __forceinline__ unsigned short f2bf_rne(float x){
    uint32_t u=fbits(x); return (unsigned short)((u+0x7fffu+((u>>16)&1u))>>16);
}
static __device__ __forceinline__ float rcp_(float x){return __builtin_amdgcn_rcpf(x);}
static __device__ __forceinline__ float exp2_(float x){return __builtin_amdgcn_exp2f(x);}
static __device__ __forceinline__ float sel4(f32x4 v, int g){
    float a = (g & 1) ? v[1] : v[0];
    float b = (g & 1) ? v[3] : v[2];
    return (g & 2) ? b : a;
}
#define MFMA __builtin_amdgcn_mfma_f32_16x16x32_bf16

// K-axis permutation (R8/R11-validated):
//   k 0..63   = h           -> W_hh[:,k]
//   k 64..98  = m f0..34    -> W_ih[:,35+f]
//   k 99..101 = x_c f32..34 -> W_ih[:,32..34]
//   k 102..127= 0
//   k 128..159= x_c f0..31  -> W_ih[:,f]
// Gate columns GATE-MAJOR: col = u + 64*G => weight row = col (identity).
// Wave-private: each wave owns 4 batch rows; ZERO barriers in the loop.
// R14 = R11 minus register pressure: kc2 gate weights + P1 weights in LDS,
// accumulators processed in two serial sweeps of 8.
static __device__ __forceinline__ float Wperm(const float* __restrict__ W_ih,
                                              const float* __restrict__ W_hh,
                                              int r, int k) {
    if (k < 64)  return W_hh[r * 64 + k];
    if (k < 99)  return W_ih[r * 70 + 35 + (k - 64)];
    if (k < 102) return W_ih[r * 70 + 32 + (k - 99)];
    if (k < 128) return 0.f;
    return W_ih[r * 70 + (k - 128)];
}

__global__ __launch_bounds__(256, 1)
void brits_main(const float* __restrict__ x_t, const float* __restrict__ masks,
                const float* __restrict__ W_ih, const float* __restrict__ W_hh,
                const float* __restrict__ b_ih, const float* __restrict__ b_hh,
                const float* __restrict__ W_reg, const float* __restrict__ b_reg,
                const float* __restrict__ W_out, const float* __restrict__ b_out,
                float* __restrict__ ws, float* __restrict__ out)
{
    __shared__ __align__(16) unsigned short stash[16 * RS];    // 61696 B bf16(m*x) -> bf16(x_c)
    __shared__ unsigned long long mbits[T_ * 16];               //  6144 B [t][row]
    __shared__ float lsum[T_ * 64];                             // 12288 B
    __shared__ __align__(16) unsigned short WBl[2][16][512];    // 32768 B gate kc3/kc4 frags
    __shared__ __align__(16) unsigned short WB2[16][512];       // 16384 B gate kc2 (m-weight) frags
    __shared__ __align__(16) unsigned short WRt[3][2][512];     //  6144 B transposed-P1 weight frags
    __shared__ __align__(16) unsigned short hb[4][2][4][64];    //  4096 B per-wave h dbuf
    __shared__ float wout[68];

    const int tid    = threadIdx.x;
    const int lane   = tid & 63;
    const int w      = tid >> 6;
    const int g      = lane >> 4;
    const int cc     = lane & 15;
    const int batch0 = blockIdx.x * 16;
    const int row    = cc & 3;          // local row this lane's A-frags carry
    const int grow   = 4 * w + row;     // block-local row 0..15

    for (int i = tid; i < 1024; i += 256) ((uint32_t*)hb)[i] = 0;   // h(0)=0
    if (tid < 65) wout[tid] = (tid < 64) ? W_out[tid] : b_out[0];

    // stash: bf16(m*x), [row][t][TS]
    for (int i = tid; i < 16 * 420; i += 256) {
        const int r = i / 420;
        const int o = (i - r * 420) * 4;
        const float4 xv = *(const float4*)(x_t   + (size_t)(batch0 + r) * 1680 + o);
        const float4 mv = *(const float4*)(masks + (size_t)(batch0 + r) * 1680 + o);
        #pragma unroll
        for (int k2 = 0; k2 < 4; ++k2) {
            const int e = o + k2, tt = e / 35, d = e - 35 * tt;
            stash[r * RS + tt * TS + d] = f2bf_rne((&mv.x)[k2] * (&xv.x)[k2]);
        }
    }
    for (int p = tid; p < 768; p += 256) {
        const int r = p & 15, tt = p >> 4;
        const float* mp = masks + (size_t)(batch0 + r) * 1680 + tt * 35;
        unsigned long long bits = 0;
        for (int d = 0; d < 35; ++d) bits |= (unsigned long long)(mp[d] != 0.f) << d;
        mbits[tt * 16 + r] = bits;
    }
    // gate kc3/kc4 weight frags -> LDS
    for (int idx = tid; idx < 16384; idx += 256) {
        const int i   = idx & 7;
        const int l   = (idx >> 3) & 63;
        const int n   = (idx >> 9) & 15;
        const int kcl = idx >> 13;
        const int k   = (3 + kcl) * 32 + 8 * (l >> 4) + i;
        const int r   = 16 * n + (l & 15);
        WBl[kcl][n][l * 8 + i] = f2bf_rne(Wperm(W_ih, W_hh, r, k));
    }
    // gate kc2 weight frags -> LDS
    for (int idx = tid; idx < 8192; idx += 256) {
        const int i = idx & 7;
        const int l = (idx >> 3) & 63;
        const int n = idx >> 9;
        const int k = 64 + 8 * (l >> 4) + i;
        const int r = 16 * n + (l & 15);
        WB2[n][l * 8 + i] = f2bf_rne(Wperm(W_ih, W_hh, r, k));
    }
    // transposed-P1 weight frags -> LDS: WRt[nt][kc][lane*8+i] = W_reg[16nt+(l&15)][kc*32+8g+i]
    for (int idx = tid; idx < 3072; idx += 256) {
        const int i  = idx & 7;
        const int l  = (idx >> 3) & 63;
        const int kc = (idx >> 9) & 1;
        const int nt = idx >> 10;
        const int rr = 16 * nt + (l & 15);
        WRt[nt][kc][l * 8 + i] =
            (rr < 35) ? f2bf_rne(W_reg[rr * 64 + kc * 32 + 8 * (l >> 4) + i]) : (unsigned short)0;
    }

    // ---- register weights: gate kc0,kc1 (h chunks) only ----
    bf16x8 Wf[16][2];
    #pragma unroll
    for (int n = 0; n < 16; ++n) {
        const int r = 16 * n + cc;
        #pragma unroll
        for (int kc = 0; kc < 2; ++kc) {
            bf16x8 v;
            #pragma unroll
            for (int i = 0; i < 8; ++i)
                v[i] = (short)f2bf_rne(Wperm(W_ih, W_hh, r, kc * 32 + 8 * g + i));
            Wf[n][kc] = v;
        }
    }
    float brg_[12];
    #pragma unroll
    for (int nt = 0; nt < 3; ++nt)
        #pragma unroll
        for (int j = 0; j < 4; ++j) {
            const int f = 16 * nt + 4 * g + j;
            brg_[nt * 4 + j] = (f < 35) ? b_reg[f] : 0.f;
        }
    float bsv[4][4];       // [q][G], pre-scaled biases for units 16q+cc
    #pragma unroll
    for (int q = 0; q < 4; ++q)
        #pragma unroll
        for (int G = 0; G < 4; ++G) {
            const int u = 16 * q + cc;
            const float raw = b_ih[G * 64 + u] + b_hh[G * 64 + u];
            bsv[q][G] = -raw * ((G == 2) ? 2.f * L2E : L2E);
        }
    __syncthreads();   // staging complete — the only barrier before the loop

    float cst[4] = {0.f, 0.f, 0.f, 0.f};
    const int srcA = cc + 32 * (g & 1);
    const int srcB = srcA + 16;
    const bool nthi = (g >> 1) != 0;

    #pragma unroll 1
    for (int t = 0; t < T_; ++t) {
        const int cur = t & 1, nxt = cur ^ 1;
        const unsigned short* hrow = &hb[w][cur][row][0];
        const bf16x8 ah0 = *(const bf16x8*)&hrow[8 * g];
        const bf16x8 ah1 = *(const bf16x8*)&hrow[32 + 8 * g];
        const unsigned long long mb = mbits[t * 16 + grow];
        const int sbase = grow * RS + t * TS;
        const uint2 xm0 = *(const uint2*)&stash[sbase + 4 * g];
        const uint2 xm1 = *(const uint2*)&stash[sbase + 16 + 4 * g];
        const uint2 xm2 = *(const uint2*)&stash[sbase + 32 + 4 * g];

        U4 c2f;   // m feats 8g..8g+7 from bitmask
        #pragma unroll
        for (int ii = 0; ii < 4; ++ii) {
            const uint32_t b2 = (uint32_t)(mb >> (8 * g + 2 * ii)) & 3u;
            c2f.u[ii] = ((b2 & 1u) ? 0x3F80u : 0u) | ((b2 & 2u) ? 0x3F800000u : 0u);
        }

        // transposed P1 (weights from LDS): p_nt[j] = x_hat[feat 16nt+4g+j][row]
        f32x4 p0 = {0,0,0,0}, p1 = {0,0,0,0}, p2 = {0,0,0,0};
        {
            const bf16x8 w00 = *(const bf16x8*)&WRt[0][0][lane * 8];
            const bf16x8 w01 = *(const bf16x8*)&WRt[0][1][lane * 8];
            const bf16x8 w10 = *(const bf16x8*)&WRt[1][0][lane * 8];
            const bf16x8 w11 = *(const bf16x8*)&WRt[1][1][lane * 8];
            const bf16x8 w20 = *(const bf16x8*)&WRt[2][0][lane * 8];
            const bf16x8 w21 = *(const bf16x8*)&WRt[2][1][lane * 8];
            p0 = MFMA(w00, ah0, p0, 0,0,0); p0 = MFMA(w01, ah1, p0, 0,0,0);
            p1 = MFMA(w10, ah0, p1, 0,0,0); p1 = MFMA(w11, ah1, p1, 0,0,0);
            p2 = MFMA(w20, ah0, p2, 0,0,0); p2 = MFMA(w21, ah1, p2, 0,0,0);
        }

        // sweep A accumulators: h + m chunks (kc0,kc1 regs; kc2 LDS)
        f32x4 acc[8];
        #pragma unroll
        for (int G = 0; G < 4; ++G)
            #pragma unroll
            for (int qq = 0; qq < 2; ++qq) {
                const int n = 4 * G + qq;
                const f32x4 z = {0,0,0,0};
                f32x4 a = MFMA(ah0, Wf[n][0], z, 0,0,0);
                a = MFMA(ah1, Wf[n][1], a, 0,0,0);
                const bf16x8 w2 = *(const bf16x8*)&WB2[n][lane * 8];
                a = MFMA(c2f.v, w2, a, 0,0,0);
                acc[G * 2 + qq] = a;
            }

        // epilogue: x_c + loss + packed bf16 pairs (R8/R11-validated)
        float lnum = 0.f;
        uint32_t P0a[3], P1a[3];
        #pragma unroll
        for (int nt = 0; nt < 3; ++nt) {
            const f32x4 pp  = (nt == 0) ? p0  : (nt == 1) ? p1  : p2;
            const uint2 xmv = (nt == 0) ? xm0 : (nt == 1) ? xm1 : xm2;
            uint32_t lo = 0, hi = 0;
            #pragma unroll
            for (int j = 0; j < 4; ++j) {
                const int f = 16 * nt + 4 * g + j;
                const float xh = pp[j] + brg_[nt * 4 + j];
                const uint32_t word = (j >> 1) ? xmv.y : xmv.x;
                const uint32_t xm16 = (j & 1) ? (word >> 16) : (word & 0xFFFFu);
                const float xmf = bitsf(xm16 << 16);
                const uint32_t bit = (uint32_t)(mb >> f) & 1u;
                const float xcv = bit ? xmf : xh;
                lnum += bit ? fabsf(xmf - xh) : 0.f;
                const uint32_t tb = fbits(xcv) & 0xFFFF0000u;
                if (j == 0)      lo  = tb >> 16;
                else if (j == 1) lo |= tb;
                else if (j == 2) hi  = tb >> 16;
                else             hi |= tb;
            }
            P0a[nt] = lo; P1a[nt] = hi;
        }
        if (cc < 4) {   // archive writers: cc == row
            *(uint2*)&stash[sbase + 4 * g]      = make_uint2(P0a[0], P1a[0]);
            *(uint2*)&stash[sbase + 16 + 4 * g] = make_uint2(P0a[1], P1a[1]);
            if (g == 0) *(uint2*)&stash[sbase + 32] = make_uint2(P0a[2], P1a[2]);
            lsum[t * 64 + w * 16 + cc * 4 + g] = lnum;
        }

        // shuffle exchange -> C4 frag = x_c[row][feats 8g..8g+7]
        const uint32_t rA0 = __shfl((int)P0a[0], srcA, 64);
        const uint32_t rA1 = __shfl((int)P1a[0], srcA, 64);
        const uint32_t rA2 = __shfl((int)P0a[1], srcA, 64);
        const uint32_t rA3 = __shfl((int)P1a[1], srcA, 64);
        const uint32_t rB0 = __shfl((int)P0a[0], srcB, 64);
        const uint32_t rB1 = __shfl((int)P1a[0], srcB, 64);
        const uint32_t rB2 = __shfl((int)P0a[1], srcB, 64);
        const uint32_t rB3 = __shfl((int)P1a[1], srcB, 64);
        U4 c4f;
        c4f.u[0] = nthi ? rA2 : rA0;
        c4f.u[1] = nthi ? rA3 : rA1;
        c4f.u[2] = nthi ? rB2 : rB0;
        c4f.u[3] = nthi ? rB3 : rB1;
        U4 c3f;   // [m32,m33 | m34,xc32 | xc33,xc34 | 0] (g==0 slots carry weight)
        {
            const uint32_t b32 = (uint32_t)(mb >> 32) & 1u;
            const uint32_t b33 = (uint32_t)(mb >> 33) & 1u;
            const uint32_t b34 = (uint32_t)(mb >> 34) & 1u;
            c3f.u[0] = (b32 ? 0x3F80u : 0u) | (b33 ? 0x3F800000u : 0u);
            c3f.u[1] = (b34 ? 0x3F80u : 0u) | (P0a[2] << 16);
            c3f.u[2] = (P0a[2] >> 16) | (P1a[2] << 16);
            c3f.u[3] = 0;
        }

        // sweep A: x_c chunks + act + h write (units 16q+cc, q=0,1)
        #pragma unroll
        for (int G = 0; G < 4; ++G)
            #pragma unroll
            for (int qq = 0; qq < 2; ++qq) {
                const int n = 4 * G + qq;
                const bf16x8 w3 = *(const bf16x8*)&WBl[0][n][lane * 8];
                const bf16x8 w4 = *(const bf16x8*)&WBl[1][n][lane * 8];
                acc[G * 2 + qq] = MFMA(c3f.v, w3, acc[G * 2 + qq], 0,0,0);
                acc[G * 2 + qq] = MFMA(c4f.v, w4, acc[G * 2 + qq], 0,0,0);
            }
        #pragma unroll
        for (int qq = 0; qq < 2; ++qq) {
            const int q = qq;
            const float gI = sel4(acc[0 * 2 + qq], g);
            const float gF = sel4(acc[1 * 2 + qq], g);
            const float gG = sel4(acc[2 * 2 + qq], g);
            const float gO = sel4(acc[3 * 2 + qq], g);
            const float iv = rcp_(1.f + exp2_(fmaf(gI, -L2E,       bsv[q][0])));
            const float fv = rcp_(1.f + exp2_(fmaf(gF, -L2E,       bsv[q][1])));
            const float gv = fmaf(2.f, rcp_(1.f + exp2_(fmaf(gG, -2.f * L2E, bsv[q][2]))), -1.f);
            const float ov = rcp_(1.f + exp2_(fmaf(gO, -L2E,       bsv[q][3])));
            const float cn = fmaf(fv, cst[q], iv * gv);
            cst[q] = cn;
            const float th = fmaf(2.f, rcp_(1.f + exp2_(cn * (-2.f * L2E))), -1.f);
            hb[w][nxt][g][16 * q + cc] = (unsigned short)(fbits(ov * th) >> 16);
        }

        // sweep B: full chunk set + act + h write (units 16q+cc, q=2,3)
        #pragma unroll
        for (int G = 0; G < 4; ++G)
            #pragma unroll
            for (int qq = 0; qq < 2; ++qq) {
                const int n = 4 * G + 2 + qq;
                const f32x4 z = {0,0,0,0};
                f32x4 a = MFMA(ah0, Wf[n][0], z, 0,0,0);
                a = MFMA(ah1, Wf[n][1], a, 0,0,0);
                const bf16x8 w2 = *(const bf16x8*)&WB2[n][lane * 8];
                a = MFMA(c2f.v, w2, a, 0,0,0);
                const bf16x8 w3 = *(const bf16x8*)&WBl[0][n][lane * 8];
                const bf16x8 w4 = *(const bf16x8*)&WBl[1][n][lane * 8];
                a = MFMA(c3f.v, w3, a, 0,0,0);
                a = MFMA(c4f.v, w4, a, 0,0,0);
                acc[G * 2 + qq] = a;
            }
        #pragma unroll
        for (int qq = 0; qq < 2; ++qq) {
            const int q = 2 + qq;
            const float gI = sel4(acc[0 * 2 + qq], g);
            const float gF = sel4(acc[1 * 2 + qq], g);
            const float gG = sel4(acc[2 * 2 + qq], g);
            const float gO = sel4(acc[3 * 2 + qq], g);
            const float iv = rcp_(1.f + exp2_(fmaf(gI, -L2E,       bsv[q][0])));
            const float fv = rcp_(1.f + exp2_(fmaf(gF, -L2E,       bsv[q][1])));
            const float gv = fmaf(2.f, rcp_(1.f + exp2_(fmaf(gG, -2.f * L2E, bsv[q][2]))), -1.f);
            const float ov = rcp_(1.f + exp2_(fmaf(gO, -L2E,       bsv[q][3])));
            const float cn = fmaf(fv, cst[q], iv * gv);
            cst[q] = cn;
            const float th = fmaf(2.f, rcp_(1.f + exp2_(cn * (-2.f * L2E))), -1.f);
            hb[w][nxt][g][16 * q + cc] = (unsigned short)(fbits(ov * th) >> 16);
        }
        // no explicit fence: hb is double-buffered and wave-private; compiler
        // tracks same-wave LDS dependencies via lgkmcnt.
    }

    __syncthreads();   // loop results visible block-wide

    // ---- loss partials ----
    if (tid < T_) {
        float num = 0.f;
        for (int i = 0; i < 64; ++i) num += lsum[tid * 64 + i];
        float den = 0.f;
        for (int r = 0; r < 16; ++r) den += (float)__popcll(mbits[tid * 16 + r]);
        atomicAdd(&ws[tid * 8 + (blockIdx.x & 7)], num);
        atomicAdd(&ws[(T_ + tid) * 8 + (blockIdx.x & 7)], den);
    }

    // ---- y_h: final h in hb[w][0] (T even) ----
    {
        float p = 0.f;
        #pragma unroll
        for (int k = 0; k < 16; ++k)
            p += bf2f(hb[w][0][row][16 * g + k]) * wout[16 * g + k];
        p += __shfl_xor(p, 16, 64);
        p += __shfl_xor(p, 32, 64);
        if (lane < 4) out[1 + batch0 + 4 * w + lane] = rcp_(1.f + exp2_(-(p + wout[64]) * L2E));
    }

    // ---- bulk dump imputations ----
    for (int i = tid; i < 16 * 1680; i += 256) {
        const int r = i / 1680;
        const int o = i - r * 1680;
        const int tt = o / 35, d = o - 35 * tt;
        out[1 + B_ + (size_t)(batch0 + r) * 1680 + o] = bf2f(stash[r * RS + tt * TS + d]);
    }
}

// loss = (1/T) * sum_t num[t] / (den[t] + 1e-5); slots spread 8-way
__global__ void post_kernel(const float* __restrict__ ws, float* __restrict__ out)
{
    const int t = threadIdx.x;  // 64 threads
    float v = 0.f;
    if (t < T_) {
        float num = 0.f, den = 0.f;
        #pragma unroll
        for (int s = 0; s < 8; ++s) {
            num += ws[t * 8 + s];
            den += ws[(T_ + t) * 8 + s];
        }
        v = num / (den + 1e-5f);
    }
    #pragma unroll
    for (int off = 1; off < 64; off <<= 1) v += __shfl_xor(v, off, 64);
    if (t == 0) out[0] = v * (1.0f / T_);
}

extern "C" void kernel_launch(void* const* d_in, const int* in_sizes, int n_in,
                              void* d_out, int out_size, void* d_ws, size_t ws_size,
                              hipStream_t stream) {
    const float* x_t   = (const float*)d_in[0];
    const float* masks = (const float*)d_in[1];
    const float* W_ih  = (const float*)d_in[6];
    const float* W_hh  = (const float*)d_in[7];
    const float* b_ih  = (const float*)d_in[8];
    const float* b_hh  = (const float*)d_in[9];
    const float* W_reg = (const float*)d_in[10];
    const float* b_reg = (const float*)d_in[11];
    const float* W_out = (const float*)d_in[14];
    const float* b_out = (const float*)d_in[15];
    float* out = (float*)d_out;
    float* ws  = (float*)d_ws;

    hipMemsetAsync(ws, 0, 2 * T_ * 8 * sizeof(float), stream);
    brits_main<<<B_ / 16, 256, 0, stream>>>(x_t, masks, W_ih, W_hh, b_ih, b_hh,
                                            W_reg, b_reg, W_out, b_out, ws, out);
    post_kernel<<<1, 64, 0, stream>>>(ws, out);
}

// Round 15
// 171.189 us; speedup vs baseline: 1.0019x; 1.0019x over previous
//
#include <hip/hip_runtime.h>
#include <stdint.h>

#define B_    4096
#define T_    48
#define D_    35
#define TS    36      // stash per-timestep stride (elems, even for uint2 align)
#define RS    1728    // stash per-row stride (elems) = 48*36
#define L2E   1.44269504f

typedef float f32x4 __attribute__((ext_vector_type(4)));
typedef short bf16x8 __attribute__((ext_vector_type(8)));
union U4 { uint32_t u[4]; bf16x8 v; };

static __device__ __forceinline__ uint32_t fbits(float x){union{float f;uint32_t u;}v;v.f=x;return v.u;}
static __device__ __forceinline__ float bitsf(uint32_t u){union{uint32_t u;float f;}v;v.u=u;return v.f;}
static __device__ __forceinline__ float bf2f(uint32_t b){return bitsf(b<<16);}
static __device__ __forceinline__ unsigned short f2bf_rne(float x){
    uint32_t u=fbits(x); return (unsigned short)((u+0x7fffu+((u>>16)&1u))>>16);
}
static __device__ __forceinline__ float rcp_(float x){return __builtin_amdgcn_rcpf(x);}
static __device__ __forceinline__ float exp2_(float x){return __builtin_amdgcn_exp2f(x);}
static __device__ __forceinline__ float sel4(f32x4 v, int g){
    float a = (g & 1) ? v[1] : v[0];
    float b = (g & 1) ? v[3] : v[2];
    return (g & 2) ? b : a;
}
#define MFMA __builtin_amdgcn_mfma_f32_16x16x32_bf16
#define SFENCE __builtin_amdgcn_sched_barrier(0)

// K-axis permutation (R8/R11/R14-validated):
//   k 0..63   = h           -> W_hh[:,k]
//   k 64..98  = m f0..34    -> W_ih[:,35+f]
//   k 99..101 = x_c f32..34 -> W_ih[:,32..34]
//   k 102..127= 0
//   k 128..159= x_c f0..31  -> W_ih[:,f]
// Gate columns GATE-MAJOR: col = u + 64*G => weight row = col (identity).
// Wave-private: each wave owns 4 batch rows; ZERO barriers in the loop.
// R15 = R14 with ALL weights in LDS (zero weight VGPRs) + sched_barrier
// fences bounding the LDS-prefetch register window.
static __device__ __forceinline__ float Wperm(const float* __restrict__ W_ih,
                                              const float* __restrict__ W_hh,
                                              int r, int k) {
    if (k < 64)  return W_hh[r * 64 + k];
    if (k < 99)  return W_ih[r * 70 + 35 + (k - 64)];
    if (k < 102) return W_ih[r * 70 + 32 + (k - 99)];
    if (k < 128) return 0.f;
    return W_ih[r * 70 + (k - 128)];
}

__global__ __launch_bounds__(256, 1)
void brits_main(const float* __restrict__ x_t, const float* __restrict__ masks,
                const float* __restrict__ W_ih, const float* __restrict__ W_hh,
                const float* __restrict__ b_ih, const float* __restrict__ b_hh,
                const float* __restrict__ W_reg, const float* __restrict__ b_reg,
                const float* __restrict__ W_out, const float* __restrict__ b_out,
                float* __restrict__ ws, float* __restrict__ out)
{
    __shared__ __align__(16) unsigned short stash[16 * RS];    // 55296 B bf16(m*x) -> bf16(x_c)
    __shared__ unsigned long long mbits[T_ * 16];               //  6144 B [t][row]
    __shared__ unsigned short lsumh[T_ * 64];                   //  6144 B bf16 loss partials
    __shared__ __align__(16) unsigned short WFl[2][16][512];    // 32768 B gate kc0/kc1 (h) frags
    __shared__ __align__(16) unsigned short WB2[16][512];       // 16384 B gate kc2 (m) frags
    __shared__ __align__(16) unsigned short WBl[2][16][512];    // 32768 B gate kc3/kc4 (xc) frags
    __shared__ __align__(16) unsigned short WRt[3][2][512];     //  6144 B transposed-P1 weight frags
    __shared__ __align__(16) unsigned short hb[4][2][4][72];    //  4608 B per-wave h dbuf (padded)
    __shared__ float wout[68];

    const int tid    = threadIdx.x;
    const int lane   = tid & 63;
    const int w      = tid >> 6;
    const int g      = lane >> 4;
    const int cc     = lane & 15;
    const int batch0 = blockIdx.x * 16;
    const int row    = cc & 3;          // local row this lane's A-frags carry
    const int grow   = 4 * w + row;     // block-local row 0..15

    for (int i = tid; i < 4 * 2 * 4 * 72 / 2; i += 256) ((uint32_t*)hb)[i] = 0;   // h(0)=0
    if (tid < 65) wout[tid] = (tid < 64) ? W_out[tid] : b_out[0];

    // stash: bf16(m*x), [row][t][TS]
    for (int i = tid; i < 16 * 420; i += 256) {
        const int r = i / 420;
        const int o = (i - r * 420) * 4;
        const float4 xv = *(const float4*)(x_t   + (size_t)(batch0 + r) * 1680 + o);
        const float4 mv = *(const float4*)(masks + (size_t)(batch0 + r) * 1680 + o);
        #pragma unroll
        for (int k2 = 0; k2 < 4; ++k2) {
            const int e = o + k2, tt = e / 35, d = e - 35 * tt;
            stash[r * RS + tt * TS + d] = f2bf_rne((&mv.x)[k2] * (&xv.x)[k2]);
        }
    }
    for (int p = tid; p < 768; p += 256) {
        const int r = p & 15, tt = p >> 4;
        const float* mp = masks + (size_t)(batch0 + r) * 1680 + tt * 35;
        unsigned long long bits = 0;
        for (int d = 0; d < 35; ++d) bits |= (unsigned long long)(mp[d] != 0.f) << d;
        mbits[tt * 16 + r] = bits;
    }
    // gate kc0/kc1 (h) frags -> LDS
    for (int idx = tid; idx < 16384; idx += 256) {
        const int i   = idx & 7;
        const int l   = (idx >> 3) & 63;
        const int n   = (idx >> 9) & 15;
        const int kcl = idx >> 13;
        const int k   = kcl * 32 + 8 * (l >> 4) + i;
        const int r   = 16 * n + (l & 15);
        WFl[kcl][n][l * 8 + i] = f2bf_rne(Wperm(W_ih, W_hh, r, k));
    }
    // gate kc2 (m) frags -> LDS
    for (int idx = tid; idx < 8192; idx += 256) {
        const int i = idx & 7;
        const int l = (idx >> 3) & 63;
        const int n = idx >> 9;
        const int k = 64 + 8 * (l >> 4) + i;
        const int r = 16 * n + (l & 15);
        WB2[n][l * 8 + i] = f2bf_rne(Wperm(W_ih, W_hh, r, k));
    }
    // gate kc3/kc4 (xc) frags -> LDS
    for (int idx = tid; idx < 16384; idx += 256) {
        const int i   = idx & 7;
        const int l   = (idx >> 3) & 63;
        const int n   = (idx >> 9) & 15;
        const int kcl = idx >> 13;
        const int k   = (3 + kcl) * 32 + 8 * (l >> 4) + i;
        const int r   = 16 * n + (l & 15);
        WBl[kcl][n][l * 8 + i] = f2bf_rne(Wperm(W_ih, W_hh, r, k));
    }
    // transposed-P1 weight frags -> LDS
    for (int idx = tid; idx < 3072; idx += 256) {
        const int i  = idx & 7;
        const int l  = (idx >> 3) & 63;
        const int kc = (idx >> 9) & 1;
        const int nt = idx >> 10;
        const int rr = 16 * nt + (l & 15);
        WRt[nt][kc][l * 8 + i] =
            (rr < 35) ? f2bf_rne(W_reg[rr * 64 + kc * 32 + 8 * (l >> 4) + i]) : (unsigned short)0;
    }

    float brg_[12];
    #pragma unroll
    for (int nt = 0; nt < 3; ++nt)
        #pragma unroll
        for (int j = 0; j < 4; ++j) {
            const int f = 16 * nt + 4 * g + j;
            brg_[nt * 4 + j] = (f < 35) ? b_reg[f] : 0.f;
        }
    float bsv[4][4];       // [q][G], pre-scaled biases for units 16q+cc
    #pragma unroll
    for (int q = 0; q < 4; ++q)
        #pragma unroll
        for (int G = 0; G < 4; ++G) {
            const int u = 16 * q + cc;
            const float raw = b_ih[G * 64 + u] + b_hh[G * 64 + u];
            bsv[q][G] = -raw * ((G == 2) ? 2.f * L2E : L2E);
        }
    __syncthreads();   // staging complete — the only barrier before the loop

    float cst[4] = {0.f, 0.f, 0.f, 0.f};
    const int srcA = cc + 32 * (g & 1);
    const int srcB = srcA + 16;
    const bool nthi = (g >> 1) != 0;

    #pragma unroll 1
    for (int t = 0; t < T_; ++t) {
        const int cur = t & 1, nxt = cur ^ 1;
        const unsigned short* hrow = &hb[w][cur][row][0];
        const bf16x8 ah0 = *(const bf16x8*)&hrow[8 * g];
        const bf16x8 ah1 = *(const bf16x8*)&hrow[32 + 8 * g];
        const unsigned long long mb = mbits[t * 16 + grow];
        const int sbase = grow * RS + t * TS;
        const uint2 xm0 = *(const uint2*)&stash[sbase + 4 * g];
        const uint2 xm1 = *(const uint2*)&stash[sbase + 16 + 4 * g];
        const uint2 xm2 = *(const uint2*)&stash[sbase + 32 + 4 * g];

        U4 c2f;   // m feats 8g..8g+7 from bitmask
        #pragma unroll
        for (int ii = 0; ii < 4; ++ii) {
            const uint32_t b2 = (uint32_t)(mb >> (8 * g + 2 * ii)) & 3u;
            c2f.u[ii] = ((b2 & 1u) ? 0x3F80u : 0u) | ((b2 & 2u) ? 0x3F800000u : 0u);
        }

        // transposed P1 (weights from LDS): p_nt[j] = x_hat[feat 16nt+4g+j][row]
        f32x4 p0 = {0,0,0,0}, p1 = {0,0,0,0}, p2 = {0,0,0,0};
        {
            const bf16x8 w00 = *(const bf16x8*)&WRt[0][0][lane * 8];
            const bf16x8 w01 = *(const bf16x8*)&WRt[0][1][lane * 8];
            const bf16x8 w10 = *(const bf16x8*)&WRt[1][0][lane * 8];
            const bf16x8 w11 = *(const bf16x8*)&WRt[1][1][lane * 8];
            const bf16x8 w20 = *(const bf16x8*)&WRt[2][0][lane * 8];
            const bf16x8 w21 = *(const bf16x8*)&WRt[2][1][lane * 8];
            p0 = MFMA(w00, ah0, p0, 0,0,0); p0 = MFMA(w01, ah1, p0, 0,0,0);
            p1 = MFMA(w10, ah0, p1, 0,0,0); p1 = MFMA(w11, ah1, p1, 0,0,0);
            p2 = MFMA(w20, ah0, p2, 0,0,0); p2 = MFMA(w21, ah1, p2, 0,0,0);
        }

        // sweep A accumulators: h + m chunks, ALL weights from LDS, fenced in
        // 4-tile windows to bound the prefetch register window
        f32x4 acc[8];
        #pragma unroll
        for (int half = 0; half < 2; ++half) {
            #pragma unroll
            for (int e = 0; e < 4; ++e) {
                const int idx = half * 4 + e;                   // 0..7
                const int G = idx >> 1, qq = idx & 1;
                const int n = 4 * G + qq;
                const f32x4 z = {0,0,0,0};
                const bf16x8 w0 = *(const bf16x8*)&WFl[0][n][lane * 8];
                const bf16x8 w1 = *(const bf16x8*)&WFl[1][n][lane * 8];
                const bf16x8 w2 = *(const bf16x8*)&WB2[n][lane * 8];
                f32x4 a = MFMA(ah0, w0, z, 0,0,0);
                a = MFMA(ah1, w1, a, 0,0,0);
                a = MFMA(c2f.v, w2, a, 0,0,0);
                acc[G * 2 + qq] = a;
            }
            SFENCE;
        }

        // epilogue: x_c + loss + packed bf16 pairs (validated R8/R11/R14)
        float lnum = 0.f;
        uint32_t P0a[3], P1a[3];
        #pragma unroll
        for (int nt = 0; nt < 3; ++nt) {
            const f32x4 pp  = (nt == 0) ? p0  : (nt == 1) ? p1  : p2;
            const uint2 xmv = (nt == 0) ? xm0 : (nt == 1) ? xm1 : xm2;
            uint32_t lo = 0, hi = 0;
            #pragma unroll
            for (int j = 0; j < 4; ++j) {
                const int f = 16 * nt + 4 * g + j;
                const float xh = pp[j] + brg_[nt * 4 + j];
                const uint32_t word = (j >> 1) ? xmv.y : xmv.x;
                const uint32_t xm16 = (j & 1) ? (word >> 16) : (word & 0xFFFFu);
                const float xmf = bitsf(xm16 << 16);
                const uint32_t bit = (uint32_t)(mb >> f) & 1u;
                const float xcv = bit ? xmf : xh;
                lnum += bit ? fabsf(xmf - xh) : 0.f;
                const uint32_t tb = fbits(xcv) & 0xFFFF0000u;
                if (j == 0)      lo  = tb >> 16;
                else if (j == 1) lo |= tb;
                else if (j == 2) hi  = tb >> 16;
                else             hi |= tb;
            }
            P0a[nt] = lo; P1a[nt] = hi;
        }
        if (cc < 4) {   // archive writers: cc == row
            *(uint2*)&stash[sbase + 4 * g]      = make_uint2(P0a[0], P1a[0]);
            *(uint2*)&stash[sbase + 16 + 4 * g] = make_uint2(P0a[1], P1a[1]);
            if (g == 0) *(uint2*)&stash[sbase + 32] = make_uint2(P0a[2], P1a[2]);
            lsumh[t * 64 + w * 16 + cc * 4 + g] = f2bf_rne(lnum);
        }

        // shuffle exchange -> C4 frag = x_c[row][feats 8g..8g+7]
        const uint32_t rA0 = __shfl((int)P0a[0], srcA, 64);
        const uint32_t rA1 = __shfl((int)P1a[0], srcA, 64);
        const uint32_t rA2 = __shfl((int)P0a[1], srcA, 64);
        const uint32_t rA3 = __shfl((int)P1a[1], srcA, 64);
        const uint32_t rB0 = __shfl((int)P0a[0], srcB, 64);
        const uint32_t rB1 = __shfl((int)P1a[0], srcB, 64);
        const uint32_t rB2 = __shfl((int)P0a[1], srcB, 64);
        const uint32_t rB3 = __shfl((int)P1a[1], srcB, 64);
        U4 c4f;
        c4f.u[0] = nthi ? rA2 : rA0;
        c4f.u[1] = nthi ? rA3 : rA1;
        c4f.u[2] = nthi ? rB2 : rB0;
        c4f.u[3] = nthi ? rB3 : rB1;
        U4 c3f;   // [m32,m33 | m34,xc32 | xc33,xc34 | 0] (g==0 slots carry weight)
        {
            const uint32_t b32 = (uint32_t)(mb >> 32) & 1u;
            const uint32_t b33 = (uint32_t)(mb >> 33) & 1u;
            const uint32_t b34 = (uint32_t)(mb >> 34) & 1u;
            c3f.u[0] = (b32 ? 0x3F80u : 0u) | (b33 ? 0x3F800000u : 0u);
            c3f.u[1] = (b34 ? 0x3F80u : 0u) | (P0a[2] << 16);
            c3f.u[2] = (P0a[2] >> 16) | (P1a[2] << 16);
            c3f.u[3] = 0;
        }
        SFENCE;

        // sweep A: x_c chunks + act + h write (units 16q+cc, q=0,1) — fenced pairs
        #pragma unroll
        for (int half = 0; half < 2; ++half) {
            #pragma unroll
            for (int e = 0; e < 4; ++e) {
                const int idx = half * 4 + e;
                const int G = idx >> 1, qq = idx & 1;
                const int n = 4 * G + qq;
                const bf16x8 w3 = *(const bf16x8*)&WBl[0][n][lane * 8];
                const bf16x8 w4 = *(const bf16x8*)&WBl[1][n][lane * 8];
                acc[G * 2 + qq] = MFMA(c3f.v, w3, acc[G * 2 + qq], 0,0,0);
                acc[G * 2 + qq] = MFMA(c4f.v, w4, acc[G * 2 + qq], 0,0,0);
            }
            SFENCE;
        }
        #pragma unroll
        for (int qq = 0; qq < 2; ++qq) {
            const int q = qq;
            const float gI = sel4(acc[0 * 2 + qq], g);
            const float gF = sel4(acc[1 * 2 + qq], g);
            const float gG = sel4(acc[2 * 2 + qq], g);
            const float gO = sel4(acc[3 * 2 + qq], g);
            const float iv = rcp_(1.f + exp2_(fmaf(gI, -L2E,       bsv[q][0])));
            const float fv = rcp_(1.f + exp2_(fmaf(gF, -L2E,       bsv[q][1])));
            const float gv = fmaf(2.f, rcp_(1.f + exp2_(fmaf(gG, -2.f * L2E, bsv[q][2]))), -1.f);
            const float ov = rcp_(1.f + exp2_(fmaf(gO, -L2E,       bsv[q][3])));
            const float cn = fmaf(fv, cst[q], iv * gv);
            cst[q] = cn;
            const float th = fmaf(2.f, rcp_(1.f + exp2_(cn * (-2.f * L2E))), -1.f);
            hb[w][nxt][g][16 * q + cc] = (unsigned short)(fbits(ov * th) >> 16);
        }

        // sweep B: full 5-chunk set per tile + act + h write (q=2,3) — fenced pairs
        #pragma unroll
        for (int pair = 0; pair < 4; ++pair) {
            #pragma unroll
            for (int e = 0; e < 2; ++e) {
                const int idx = pair * 2 + e;                   // 0..7
                const int G = idx >> 1, qq = idx & 1;
                const int n = 4 * G + 2 + qq;
                const f32x4 z = {0,0,0,0};
                const bf16x8 w0 = *(const bf16x8*)&WFl[0][n][lane * 8];
                const bf16x8 w1 = *(const bf16x8*)&WFl[1][n][lane * 8];
                const bf16x8 w2 = *(const bf16x8*)&WB2[n][lane * 8];
                const bf16x8 w3 = *(const bf16x8*)&WBl[0][n][lane * 8];
                const bf16x8 w4 = *(const bf16x8*)&WBl[1][n][lane * 8];
                f32x4 a = MFMA(ah0, w0, z, 0,0,0);
                a = MFMA(ah1, w1, a, 0,0,0);
                a = MFMA(c2f.v, w2, a, 0,0,0);
                a = MFMA(c3f.v, w3, a, 0,0,0);
                a = MFMA(c4f.v, w4, a, 0,0,0);
                acc[G * 2 + qq] = a;
            }
            SFENCE;
        }
        #pragma unroll
        for (int qq = 0; qq < 2; ++qq) {
            const int q = 2 + qq;
            const float gI = sel4(acc[0 * 2 + qq], g);
            const float gF = sel4(acc[1 * 2 + qq], g);
            const float gG = sel4(acc[2 * 2 + qq], g);
            const float gO = sel4(acc[3 * 2 + qq], g);
            const float iv = rcp_(1.f + exp2_(fmaf(gI, -L2E,       bsv[q][0])));
            const float fv = rcp_(1.f + exp2_(fmaf(gF, -L2E,       bsv[q][1])));
            const float gv = fmaf(2.f, rcp_(1.f + exp2_(fmaf(gG, -2.f * L2E, bsv[q][2]))), -1.f);
            const float ov = rcp_(1.f + exp2_(fmaf(gO, -L2E,       bsv[q][3])));
            const float cn = fmaf(fv, cst[q], iv * gv);
            cst[q] = cn;
            const float th = fmaf(2.f, rcp_(1.f + exp2_(cn * (-2.f * L2E))), -1.f);
            hb[w][nxt][g][16 * q + cc] = (unsigned short)(fbits(ov * th) >> 16);
        }
        // hb is double-buffered and wave-private; same-wave lgkm ordering suffices.
    }

    __syncthreads();   // loop results visible block-wide

    // ---- loss partials ----
    if (tid < T_) {
        float num = 0.f;
        for (int i = 0; i < 64; ++i) num += bf2f((uint32_t)lsumh[tid * 64 + i]);
        float den = 0.f;
        for (int r = 0; r < 16; ++r) den += (float)__popcll(mbits[tid * 16 + r]);
        atomicAdd(&ws[tid * 8 + (blockIdx.x & 7)], num);
        atomicAdd(&ws[(T_ + tid) * 8 + (blockIdx.x & 7)], den);
    }

    // ---- y_h: final h in hb[w][0] (T even) ----
    {
        float p = 0.f;
        #pragma unroll
        for (int k = 0; k < 16; ++k)
            p += bf2f((uint32_t)hb[w][0][row][16 * g + k]) * wout[16 * g + k];
        p += __shfl_xor(p, 16, 64);
        p += __shfl_xor(p, 32, 64);
        if (lane < 4) out[1 + batch0 + 4 * w + lane] = rcp_(1.f + exp2_(-(p + wout[64]) * L2E));
    }

    // ---- bulk dump imputations ----
    for (int i = tid; i < 16 * 1680; i += 256) {
        const int r = i / 1680;
        const int o = i - r * 1680;
        const int tt = o / 35, d = o - 35 * tt;
        out[1 + B_ + (size_t)(batch0 + r) * 1680 + o] = bf2f((uint32_t)stash[r * RS + tt * TS + d]);
    }
}

// loss = (1/T) * sum_t num[t] / (den[t] + 1e-5); slots spread 8-way
__global__ void post_kernel(const float* __restrict__ ws, float* __restrict__ out)
{
    const int t = threadIdx.x;  // 64 threads
    float v = 0.f;
    if (t < T_) {
        float num = 0.f, den = 0.f;
        #pragma unroll
        for (int s = 0; s < 8; ++s) {
            num += ws[t * 8 + s];
            den += ws[(T_ + t) * 8 + s];
        }
        v = num / (den + 1e-5f);
    }
    #pragma unroll
    for (int off = 1; off < 64; off <<= 1) v += __shfl_xor(v, off, 64);
    if (t == 0) out[0] = v * (1.0f / T_);
}

extern "C" void kernel_launch(void* const* d_in, const int* in_sizes, int n_in,
                              void* d_out, int out_size, void* d_ws, size_t ws_size,
                              hipStream_t stream) {
    const float* x_t   = (const float*)d_in[0];
    const float* masks = (const float*)d_in[1];
    const float* W_ih  = (const float*)d_in[6];
    const float* W_hh  = (const float*)d_in[7];
    const float* b_ih  = (const float*)d_in[8];
    const float* b_hh  = (const float*)d_in[9];
    const float* W_reg = (const float*)d_in[10];
    const float* b_reg = (const float*)d_in[11];
    const float* W_out = (const float*)d_in[14];
    const float* b_out = (const float*)d_in[15];
    float* out = (float*)d_out;
    float* ws  = (float*)d_ws;

    hipMemsetAsync(ws, 0, 2 * T_ * 8 * sizeof(float), stream);
    brits_main<<<B_ / 16, 256, 0, stream>>>(x_t, masks, W_ih, W_hh, b_ih, b_hh,
                                            W_reg, b_reg, W_out, b_out, ws, out);
    post_kernel<<<1, 64, 0, stream>>>(ws, out);
}

// Round 16
// 85.974 us; speedup vs baseline: 1.9949x; 1.9912x over previous
//
#include <hip/hip_runtime.h>
#include <stdint.h>

#define B_    4096
#define T_    48
#define D_    35
#define KROW  168           // A-row stride (elems); MFMA reads k 0..159; 136..167 zero
#define ROWEL (T_ * D_)     // 1680
#define L2E   1.44269504f

typedef float f32x4 __attribute__((ext_vector_type(4)));
typedef short bf16x8 __attribute__((ext_vector_type(8)));

static __device__ __forceinline__ uint32_t fbits(float x){union{float f;uint32_t u;}v;v.f=x;return v.u;}
static __device__ __forceinline__ float bitsf(uint32_t u){union{uint32_t u;float f;}v;v.u=u;return v.f;}
static __device__ __forceinline__ float bf2f(unsigned short b){return bitsf(((uint32_t)b)<<16);}
static __device__ __forceinline__ unsigned short f2bf_rne(float x){
    uint32_t u=fbits(x); return (unsigned short)((u+0x7fffu+((u>>16)&1u))>>16);
}
static __device__ __forceinline__ float rcp_(float x){return __builtin_amdgcn_rcpf(x);}
static __device__ __forceinline__ float exp2_(float x){return __builtin_amdgcn_exp2f(x);}

#define MFMA __builtin_amdgcn_mfma_f32_16x16x32_bf16

// K-axis layout (A tile and weight fragments):
//   k 0..34 = x_c -> W_ih[:,0:35] ; k 35..69 = m -> W_ih[:,35:70]
//   k 70..71 = 0  ; k 72..135 = h -> W_hh   ; k 136..159 = 0
// Wave specialization (8 waves): waves 0..3 = gates (pre-bar kk2..kk4; post-bar
// kk0,kk1 + cell update + h write). Waves 4..6 = P1 + epilogue (x_c, m(t+1)
// pre-write, stash archive, loss). Wave 7 idle in loop.

__global__ __launch_bounds__(512, 1)
void brits_main(const float* __restrict__ x_t, const float* __restrict__ masks,
                const float* __restrict__ W_ih, const float* __restrict__ W_hh,
                const float* __restrict__ b_ih, const float* __restrict__ b_hh,
                const float* __restrict__ W_reg, const float* __restrict__ b_reg,
                const float* __restrict__ W_out, const float* __restrict__ b_out,
                float* __restrict__ ws, float* __restrict__ out)
{
    __shared__ __align__(16) unsigned short Abuf[2][16 * KROW];   // 10752 B
    __shared__ __align__(16) unsigned short stash[16 * ROWEL];    // 53760 B: bf16(m*x) -> bf16(x_c)
    __shared__ unsigned long long mbits[16 * T_];                 //  6144 B: [r][t]
    __shared__ float lsum[T_ * 3 * 64];                           // 36864 B
    __shared__ float wout[65];

    const int tid    = threadIdx.x;
    const int lane   = tid & 63;
    const int w      = tid >> 6;      // wave 0..7
    const int g      = lane >> 4;     // k-subgroup / C row-group
    const int cc     = lane & 15;
    const int batch0 = blockIdx.x * 16;
    const int u      = (w & 3) * 16 + cc;   // gate unit (w<4)
    const int u2     = (w - 4) * 16 + cc;   // x_hat col (w in 4..6)

    // ---- staging (512 threads) ----
    for (int i = tid; i < 16 * KROW; i += 512) ((uint32_t*)Abuf)[i] = 0;  // both buffers
    if (tid < 65) wout[tid] = (tid < 64) ? W_out[tid] : b_out[0];

    for (int i = tid; i < 16 * 210; i += 512) {
        const int r = i / 210;
        const int o = (i - r * 210) * 8;
        const float* xp = x_t   + (size_t)(batch0 + r) * ROWEL + o;
        const float* mp = masks + (size_t)(batch0 + r) * ROWEL + o;
        float xv[8], mv[8];
        *(float4*)&xv[0] = *(const float4*)xp; *(float4*)&xv[4] = *(const float4*)(xp + 4);
        *(float4*)&mv[0] = *(const float4*)mp; *(float4*)&mv[4] = *(const float4*)(mp + 4);
        unsigned short pk[8];
        #pragma unroll
        for (int k = 0; k < 8; ++k) pk[k] = f2bf_rne(mv[k] * xv[k]);
        *(uint4*)&stash[r * ROWEL + o] = *(const uint4*)pk;
    }
    for (int p = tid; p < 16 * T_; p += 512) {
        const int r = p / T_, t = p - r * T_;
        const float* mp = masks + (size_t)(batch0 + r) * ROWEL + t * D_;
        unsigned long long bits = 0;
        for (int d = 0; d < D_; ++d) bits |= (unsigned long long)(mp[d] != 0.f) << d;
        mbits[p] = bits;
    }

    // ---- weights -> registers (per wave group) ----
    bf16x8 Wf[4][5];                 // gate waves only
    float bIs = 0.f, bFs = 0.f, bGs = 0.f, bOs = 0.f;
    if (w < 4) {
        #pragma unroll
        for (int G = 0; G < 4; ++G) {
            const int n = G * 64 + u;
            #pragma unroll
            for (int kc = 0; kc < 5; ++kc) {
                bf16x8 v;
                #pragma unroll
                for (int i = 0; i < 8; ++i) {
                    const int k = kc * 32 + 8 * g + i;
                    float f = 0.f;
                    if (k < 70)                  f = W_ih[n * 70 + k];
                    else if (k >= 72 && k < 136) f = W_hh[n * 64 + (k - 72)];
                    v[i] = (short)f2bf_rne(f);
                }
                Wf[G][kc] = v;
            }
        }
        bIs = -(b_ih[u]       + b_hh[u])       * L2E;
        bFs = -(b_ih[64 + u]  + b_hh[64 + u])  * L2E;
        bGs = -(b_ih[128 + u] + b_hh[128 + u]) * 2.f * L2E;
        bOs = -(b_ih[192 + u] + b_hh[192 + u]) * L2E;
    }
    bf16x8 Wr0 = {0,0,0,0,0,0,0,0}, Wr1 = {0,0,0,0,0,0,0,0};
    float brg = 0.f;
    const bool pw = (w >= 4) && (w < 7);      // P1 waves
    const bool pl = pw && (u2 < 35);          // epilogue-active lanes
    if (pl) {
        #pragma unroll
        for (int i = 0; i < 8; ++i) {
            Wr0[i] = (short)f2bf_rne(W_reg[u2 * 64 + 8 * g + i]);
            Wr1[i] = (short)f2bf_rne(W_reg[u2 * 64 + 32 + 8 * g + i]);
        }
        brg = b_reg[u2];
    }
    __syncthreads();   // stash + mbits ready

    // ---- per-lane mask bitmaps over t, first m*x prefetch, m(0) pre-write ----
    unsigned long long PM[4] = {0, 0, 0, 0};
    uint32_t xmr[4] = {0, 0, 0, 0};
    if (pl) {
        #pragma unroll
        for (int j = 0; j < 4; ++j) {
            const int row = 4 * g + j;
            unsigned long long pm = 0;
            for (int t = 0; t < T_; ++t)
                pm |= ((mbits[row * T_ + t] >> u2) & 1ull) << t;
            PM[j] = pm;
            xmr[j] = stash[row * ROWEL + u2];                      // t=0
            Abuf[0][row * KROW + 35 + u2] = (pm & 1ull) ? (unsigned short)0x3F80 : (unsigned short)0;
        }
    }
    __syncthreads();   // m(0) visible

    float c_[4] = {0.f, 0.f, 0.f, 0.f};

    for (int t = 0; t < T_; ++t) {
        unsigned short* A  = Abuf[t & 1];
        unsigned short* An = Abuf[(t + 1) & 1];

        f32x4 gI = {0,0,0,0}, gF = {0,0,0,0}, gG = {0,0,0,0}, gO = {0,0,0,0};

        if (w < 4) {
            // ---- gate waves pre-bar1: h/m chunks kk2..kk4 ----
            bf16x8 a2 = *(const bf16x8*)&A[cc * KROW + 64  + 8 * g];
            bf16x8 a3 = *(const bf16x8*)&A[cc * KROW + 96  + 8 * g];
            bf16x8 a4 = *(const bf16x8*)&A[cc * KROW + 128 + 8 * g];
            gI = MFMA(a2, Wf[0][2], gI, 0,0,0);
            gF = MFMA(a2, Wf[1][2], gF, 0,0,0);
            gG = MFMA(a2, Wf[2][2], gG, 0,0,0);
            gO = MFMA(a2, Wf[3][2], gO, 0,0,0);
            gI = MFMA(a3, Wf[0][3], gI, 0,0,0);
            gF = MFMA(a3, Wf[1][3], gF, 0,0,0);
            gG = MFMA(a3, Wf[2][3], gG, 0,0,0);
            gO = MFMA(a3, Wf[3][3], gO, 0,0,0);
            gI = MFMA(a4, Wf[0][4], gI, 0,0,0);
            gF = MFMA(a4, Wf[1][4], gF, 0,0,0);
            gG = MFMA(a4, Wf[2][4], gG, 0,0,0);
            gO = MFMA(a4, Wf[3][4], gO, 0,0,0);
        } else if (pw) {
            // ---- P1 waves: x_hat, epilogue, x_c/m/stash/loss ----
            bf16x8 ah0 = *(const bf16x8*)&A[cc * KROW + 72  + 8 * g];
            bf16x8 ah1 = *(const bf16x8*)&A[cc * KROW + 104 + 8 * g];
            f32x4 p0 = {0,0,0,0};
            p0 = MFMA(ah0, Wr0, p0, 0,0,0);
            p0 = MFMA(ah1, Wr1, p0, 0,0,0);
            float lnum = 0.f;
            if (u2 < 35) {
                #pragma unroll
                for (int j = 0; j < 4; ++j) {
                    const int row = 4 * g + j;
                    const float xh = p0[j] + brg;
                    const float xm = bf2f((unsigned short)xmr[j]);
                    const uint32_t mb = (uint32_t)(PM[j] >> t) & 1u;
                    lnum += mb ? fabsf(xm - xh) : 0.f;
                    const unsigned short xc16 = mb ? (unsigned short)xmr[j] : f2bf_rne(xh);
                    A[row * KROW + u2] = xc16;                              // x_c(t)
                    An[row * KROW + 35 + u2] =                              // m(t+1), one step ahead
                        ((PM[j] >> (t + 1)) & 1ull) ? (unsigned short)0x3F80 : (unsigned short)0;
                    stash[row * ROWEL + t * D_ + u2] = xc16;                // imputation archive
                }
            }
            lsum[(t * 3 + (w - 4)) * 64 + lane] = lnum;
        }
        __syncthreads();   // bar1 (lgkm only): x_c visible

        if (w < 4) {
            // ---- gate waves post-bar1: x_c chunks + cell update + h write ----
            bf16x8 a0 = *(const bf16x8*)&A[cc * KROW + 0  + 8 * g];
            bf16x8 a1 = *(const bf16x8*)&A[cc * KROW + 32 + 8 * g];
            gI = MFMA(a0, Wf[0][0], gI, 0,0,0);
            gF = MFMA(a0, Wf[1][0], gF, 0,0,0);
            gG = MFMA(a0, Wf[2][0], gG, 0,0,0);
            gO = MFMA(a0, Wf[3][0], gO, 0,0,0);
            gI = MFMA(a1, Wf[0][1], gI, 0,0,0);
            gF = MFMA(a1, Wf[1][1], gF, 0,0,0);
            gG = MFMA(a1, Wf[2][1], gG, 0,0,0);
            gO = MFMA(a1, Wf[3][1], gO, 0,0,0);
            #pragma unroll
            for (int j = 0; j < 4; ++j) {
                const float iv = rcp_(1.f + exp2_(fmaf(gI[j], -L2E,       bIs)));
                const float fv = rcp_(1.f + exp2_(fmaf(gF[j], -L2E,       bFs)));
                const float gv = fmaf(2.f, rcp_(1.f + exp2_(fmaf(gG[j], -2.f * L2E, bGs))), -1.f);
                const float ov = rcp_(1.f + exp2_(fmaf(gO[j], -L2E,       bOs)));
                const float cn = fmaf(fv, c_[j], iv * gv);
                c_[j] = cn;
                const float th = fmaf(2.f, rcp_(1.f + exp2_(cn * (-2.f * L2E))), -1.f);
                An[(4 * g + j) * KROW + 72 + u] = (unsigned short)(fbits(ov * th) >> 16);
            }
        } else if (pl && t + 1 < T_) {
            #pragma unroll
            for (int j = 0; j < 4; ++j)                  // prefetch next step's m*x
                xmr[j] = stash[(4 * g + j) * ROWEL + (t + 1) * D_ + u2];
        }
        __syncthreads();   // bar2 (lgkm only): h(t) visible
    }

    // ---- loss partials: per-t reduce + spread atomics (once per block) ----
    if (tid < T_) {
        const int t = tid;
        float num = 0.f;
        for (int i = 0; i < 192; ++i) num += lsum[t * 192 + i];
        float den = 0.f;
        for (int r = 0; r < 16; ++r) den += (float)__popcll(mbits[r * T_ + t]);
        atomicAdd(&ws[t * 8 + (blockIdx.x & 7)], num);
        atomicAdd(&ws[(T_ + t) * 8 + (blockIdx.x & 7)], den);
    }

    // ---- y_h = sigmoid(h(T-1) @ W_out^T + b_out); h(T-1) in Abuf[0] ----
    if (w == 1) {
        float p = 0.f;
        #pragma unroll
        for (int k = 0; k < 16; ++k)
            p += bf2f(Abuf[0][cc * KROW + 72 + 16 * g + k]) * wout[16 * g + k];
        p += __shfl_xor(p, 16, 64);
        p += __shfl_xor(p, 32, 64);
        if (lane < 16) out[1 + batch0 + cc] = rcp_(1.f + exp2_(-(p + wout[64]) * L2E));
    }

    // ---- bulk dump imputations ----
    for (int i = tid; i < 16 * ROWEL; i += 512) {
        const int r = i / ROWEL;
        const int o = i - r * ROWEL;
        out[1 + B_ + (size_t)(batch0 + r) * ROWEL + o] = bf2f(stash[i]);
    }
}

// loss = (1/T) * sum_t num[t] / (den[t] + 1e-5); slots spread 8-way
__global__ void post_kernel(const float* __restrict__ ws, float* __restrict__ out)
{
    const int t = threadIdx.x;  // 64 threads
    float v = 0.f;
    if (t < T_) {
        float num = 0.f, den = 0.f;
        #pragma unroll
        for (int s = 0; s < 8; ++s) {
            num += ws[t * 8 + s];
            den += ws[(T_ + t) * 8 + s];
        }
        v = num / (den + 1e-5f);
    }
    #pragma unroll
    for (int off = 1; off < 64; off <<= 1) v += __shfl_xor(v, off, 64);
    if (t == 0) out[0] = v * (1.0f / T_);
}

extern "C" void kernel_launch(void* const* d_in, const int* in_sizes, int n_in,
                              void* d_out, int out_size, void* d_ws, size_t ws_size,
                              hipStream_t stream) {
    const float* x_t   = (const float*)d_in[0];
    const float* masks = (const float*)d_in[1];
    const float* W_ih  = (const float*)d_in[6];
    const float* W_hh  = (const float*)d_in[7];
    const float* b_ih  = (const float*)d_in[8];
    const float* b_hh  = (const float*)d_in[9];
    const float* W_reg = (const float*)d_in[10];
    const float* b_reg = (const float*)d_in[11];
    const float* W_out = (const float*)d_in[14];
    const float* b_out = (const float*)d_in[15];
    float* out = (float*)d_out;
    float* ws  = (float*)d_ws;

    hipMemsetAsync(ws, 0, 2 * T_ * 8 * sizeof(float), stream);
    brits_main<<<B_ / 16, 512, 0, stream>>>(x_t, masks, W_ih, W_hh, b_ih, b_hh,
                                            W_reg, b_reg, W_out, b_out, ws, out);
    post_kernel<<<1, 64, 0, stream>>>(ws, out);
}

// Round 17
// 78.081 us; speedup vs baseline: 2.1966x; 1.1011x over previous
//
#include <hip/hip_runtime.h>
#include <stdint.h>

#define B_    4096
#define T_    48
#define D_    35
#define KROW  168           // A-row stride (elems); MFMA reads k 0..159; 136..167 zero
#define ROWEL (T_ * D_)     // 1680
#define L2E   1.44269504f

typedef float f32x4 __attribute__((ext_vector_type(4)));
typedef short bf16x8 __attribute__((ext_vector_type(8)));

static __device__ __forceinline__ uint32_t fbits(float x){union{float f;uint32_t u;}v;v.f=x;return v.u;}
static __device__ __forceinline__ float bitsf(uint32_t u){union{uint32_t u;float f;}v;v.u=u;return v.f;}
static __device__ __forceinline__ float bf2f(unsigned short b){return bitsf(((uint32_t)b)<<16);}
static __device__ __forceinline__ unsigned short f2bf_rne(float x){
    uint32_t u=fbits(x); return (unsigned short)((u+0x7fffu+((u>>16)&1u))>>16);
}
static __device__ __forceinline__ float rcp_(float x){return __builtin_amdgcn_rcpf(x);}
static __device__ __forceinline__ float exp2_(float x){return __builtin_amdgcn_exp2f(x);}

#define MFMA __builtin_amdgcn_mfma_f32_16x16x32_bf16

// Raw per-step barrier: drains LDS only (global loads/stores stay in flight).
static __device__ __forceinline__ void step_barrier() {
    asm volatile("s_waitcnt lgkmcnt(0)" ::: "memory");
    __builtin_amdgcn_s_barrier();
    __builtin_amdgcn_sched_barrier(0);
}

// K-axis layout (A tile and weight fragments):
//   k 0..34 = x_c -> W_ih[:,0:35] ; k 35..69 = m -> W_ih[:,35:70]
//   k 70..71 = 0  ; k 72..135 = h -> W_hh   ; k 136..159 = 0
// Wave roles (8 waves): w0..3 = gates (pre-bar kk2..kk4; post-bar kk0,kk1 +
// cell update + h write). w4..6 = P1 + epilogue: x_hat from h; x_c->A;
// imputation (f32, m ? x : x_hat) -> global fire-and-forget; loss->lsum.
// x streamed from GLOBAL with a 2-deep prefetch (load t+2 while computing t)
// — no m*x stash, no staging pass for x.

__global__ __launch_bounds__(512, 1)
void brits_main(const float* __restrict__ x_t, const float* __restrict__ masks,
                const float* __restrict__ W_ih, const float* __restrict__ W_hh,
                const float* __restrict__ b_ih, const float* __restrict__ b_hh,
                const float* __restrict__ W_reg, const float* __restrict__ b_reg,
                const float* __restrict__ W_out, const float* __restrict__ b_out,
                float* __restrict__ ws, float* __restrict__ out)
{
    __shared__ __align__(16) unsigned short Abuf[2][16 * KROW];   // 10752 B
    __shared__ unsigned long long mbits[16 * T_];                 //  6144 B: [r][t]
    __shared__ float lsum[T_ * 3 * 64];                           // 36864 B
    __shared__ float wout[65];

    const int tid    = threadIdx.x;
    const int lane   = tid & 63;
    const int w      = tid >> 6;      // wave 0..7
    const int g      = lane >> 4;     // k-subgroup / C row-group
    const int cc     = lane & 15;
    const int batch0 = blockIdx.x * 16;
    const int u      = (w & 3) * 16 + cc;   // gate unit (w<4)
    const int u2     = (w - 4) * 16 + cc;   // x_hat col (w in 4..6)

    // ---- staging (512 threads): Abuf zero + mbits only ----
    for (int i = tid; i < 16 * KROW; i += 512) ((uint32_t*)Abuf)[i] = 0;  // both buffers
    if (tid < 65) wout[tid] = (tid < 64) ? W_out[tid] : b_out[0];

    for (int p = tid; p < 16 * T_; p += 512) {
        const int r = p / T_, t = p - r * T_;
        const float* mp = masks + (size_t)(batch0 + r) * ROWEL + t * D_;
        unsigned long long bits = 0;
        for (int d = 0; d < D_; ++d) bits |= (unsigned long long)(mp[d] != 0.f) << d;
        mbits[p] = bits;
    }

    // ---- weights -> registers (per wave role) ----
    bf16x8 Wf[4][5];                 // gate waves only
    float bIs = 0.f, bFs = 0.f, bGs = 0.f, bOs = 0.f;
    if (w < 4) {
        #pragma unroll
        for (int G = 0; G < 4; ++G) {
            const int n = G * 64 + u;
            #pragma unroll
            for (int kc = 0; kc < 5; ++kc) {
                bf16x8 v;
                #pragma unroll
                for (int i = 0; i < 8; ++i) {
                    const int k = kc * 32 + 8 * g + i;
                    float f = 0.f;
                    if (k < 70)                  f = W_ih[n * 70 + k];
                    else if (k >= 72 && k < 136) f = W_hh[n * 64 + (k - 72)];
                    v[i] = (short)f2bf_rne(f);
                }
                Wf[G][kc] = v;
            }
        }
        bIs = -(b_ih[u]       + b_hh[u])       * L2E;
        bFs = -(b_ih[64 + u]  + b_hh[64 + u])  * L2E;
        bGs = -(b_ih[128 + u] + b_hh[128 + u]) * 2.f * L2E;
        bOs = -(b_ih[192 + u] + b_hh[192 + u]) * L2E;
    }
    bf16x8 Wr0 = {0,0,0,0,0,0,0,0}, Wr1 = {0,0,0,0,0,0,0,0};
    float brg = 0.f;
    const bool pw = (w >= 4) && (w < 7);      // P1 waves
    const bool pl = pw && (u2 < 35);          // epilogue-active lanes
    if (pl) {
        #pragma unroll
        for (int i = 0; i < 8; ++i) {
            Wr0[i] = (short)f2bf_rne(W_reg[u2 * 64 + 8 * g + i]);
            Wr1[i] = (short)f2bf_rne(W_reg[u2 * 64 + 32 + 8 * g + i]);
        }
        brg = b_reg[u2];
    }
    __syncthreads();   // mbits ready (full drain OK, once)

    // ---- P1 per-lane state: mask-over-t bitmaps, x row pointers, m(0) pre-write ----
    unsigned long long PM[4] = {0, 0, 0, 0};
    const float* xrow[4];
    float* orow[4];
    float xrA[4] = {0.f, 0.f, 0.f, 0.f};   // x for even t
    float xrB[4] = {0.f, 0.f, 0.f, 0.f};   // x for odd t
    if (pl) {
        #pragma unroll
        for (int j = 0; j < 4; ++j) {
            const int row = 4 * g + j;
            unsigned long long pm = 0;
            for (int t = 0; t < T_; ++t)
                pm |= ((mbits[row * T_ + t] >> u2) & 1ull) << t;
            PM[j] = pm;
            xrow[j] = x_t + (size_t)(batch0 + row) * ROWEL + u2;
            orow[j] = out + 1 + B_ + (size_t)(batch0 + row) * ROWEL + u2;
            xrA[j] = xrow[j][0];                  // t=0
            xrB[j] = xrow[j][D_];                 // t=1
            Abuf[0][row * KROW + 35 + u2] = (pm & 1ull) ? (unsigned short)0x3F80 : (unsigned short)0;
        }
    }
    __syncthreads();   // m(0) visible

    float c_[4] = {0.f, 0.f, 0.f, 0.f};

    // one recurrence step; xr = this step's x values (refilled with t+2's)
    auto step = [&](int t, float (&xr)[4]) {
        unsigned short* A  = Abuf[t & 1];
        unsigned short* An = Abuf[(t + 1) & 1];

        f32x4 gIa = {0,0,0,0}, gFa = {0,0,0,0}, gGa = {0,0,0,0}, gOa = {0,0,0,0};
        f32x4 gIb = {0,0,0,0}, gFb = {0,0,0,0}, gGb = {0,0,0,0}, gOb = {0,0,0,0};

        if (w < 4) {
            // ---- gate waves pre-bar: h/m chunks kk2..kk4, two parallel acc chains ----
            bf16x8 a2 = *(const bf16x8*)&A[cc * KROW + 64  + 8 * g];
            bf16x8 a3 = *(const bf16x8*)&A[cc * KROW + 96  + 8 * g];
            bf16x8 a4 = *(const bf16x8*)&A[cc * KROW + 128 + 8 * g];
            gIa = MFMA(a2, Wf[0][2], gIa, 0,0,0);
            gFa = MFMA(a2, Wf[1][2], gFa, 0,0,0);
            gGa = MFMA(a2, Wf[2][2], gGa, 0,0,0);
            gOa = MFMA(a2, Wf[3][2], gOa, 0,0,0);
            gIb = MFMA(a3, Wf[0][3], gIb, 0,0,0);
            gFb = MFMA(a3, Wf[1][3], gFb, 0,0,0);
            gGb = MFMA(a3, Wf[2][3], gGb, 0,0,0);
            gOb = MFMA(a3, Wf[3][3], gOb, 0,0,0);
            gIa = MFMA(a4, Wf[0][4], gIa, 0,0,0);
            gFa = MFMA(a4, Wf[1][4], gFa, 0,0,0);
            gGa = MFMA(a4, Wf[2][4], gGa, 0,0,0);
            gOa = MFMA(a4, Wf[3][4], gOa, 0,0,0);
        } else if (pw) {
            // ---- P1 waves: x_hat, epilogue: x_c->A, f32 imputation->global, loss ----
            bf16x8 ah0 = *(const bf16x8*)&A[cc * KROW + 72  + 8 * g];
            bf16x8 ah1 = *(const bf16x8*)&A[cc * KROW + 104 + 8 * g];
            f32x4 p0 = {0,0,0,0};
            p0 = MFMA(ah0, Wr0, p0, 0,0,0);
            p0 = MFMA(ah1, Wr1, p0, 0,0,0);
            float lnum = 0.f;
            if (pl) {
                #pragma unroll
                for (int j = 0; j < 4; ++j) {
                    const int row = 4 * g + j;
                    const float xh = p0[j] + brg;
                    const uint32_t mb = (uint32_t)(PM[j] >> t) & 1u;
                    const float xv = xr[j];
                    lnum += mb ? fabsf(xv - xh) : 0.f;
                    const float xc = mb ? xv : xh;
                    A[row * KROW + u2] = f2bf_rne(xc);                      // x_c(t) for gates
                    An[row * KROW + 35 + u2] =                              // m(t+1), one step ahead
                        ((PM[j] >> (t + 1)) & 1ull) ? (unsigned short)0x3F80 : (unsigned short)0;
                    orow[j][t * D_] = xc;                                   // f32 imputation, fire-and-forget
                }
            }
            lsum[(t * 3 + (w - 4)) * 64 + lane] = lnum;
        }
        step_barrier();   // bar1 (LDS drain only): x_c visible; global ops in flight

        if (w < 4) {
            // ---- gate waves post-bar: x_c chunks + merge + act + h write ----
            bf16x8 a0 = *(const bf16x8*)&A[cc * KROW + 0  + 8 * g];
            bf16x8 a1 = *(const bf16x8*)&A[cc * KROW + 32 + 8 * g];
            gIa = MFMA(a0, Wf[0][0], gIa, 0,0,0);
            gFa = MFMA(a0, Wf[1][0], gFa, 0,0,0);
            gGa = MFMA(a0, Wf[2][0], gGa, 0,0,0);
            gOa = MFMA(a0, Wf[3][0], gOa, 0,0,0);
            gIb = MFMA(a1, Wf[0][1], gIb, 0,0,0);
            gFb = MFMA(a1, Wf[1][1], gFb, 0,0,0);
            gGb = MFMA(a1, Wf[2][1], gGb, 0,0,0);
            gOb = MFMA(a1, Wf[3][1], gOb, 0,0,0);
            const f32x4 gI = gIa + gIb;
            const f32x4 gF = gFa + gFb;
            const f32x4 gG = gGa + gGb;
            const f32x4 gO = gOa + gOb;
            #pragma unroll
            for (int j = 0; j < 4; ++j) {
                const float iv = rcp_(1.f + exp2_(fmaf(gI[j], -L2E,       bIs)));
                const float fv = rcp_(1.f + exp2_(fmaf(gF[j], -L2E,       bFs)));
                const float gv = fmaf(2.f, rcp_(1.f + exp2_(fmaf(gG[j], -2.f * L2E, bGs))), -1.f);
                const float ov = rcp_(1.f + exp2_(fmaf(gO[j], -L2E,       bOs)));
                const float cn = fmaf(fv, c_[j], iv * gv);
                c_[j] = cn;
                const float th = fmaf(2.f, rcp_(1.f + exp2_(cn * (-2.f * L2E))), -1.f);
                An[(4 * g + j) * KROW + 72 + u] = (unsigned short)(fbits(ov * th) >> 16);
            }
        } else if (pl && t + 2 < T_) {
            #pragma unroll
            for (int j = 0; j < 4; ++j)                  // 2-deep prefetch: x(t+2)
                xr[j] = xrow[j][(t + 2) * D_];
        }
        step_barrier();   // bar2 (LDS drain only): h(t) visible
    };

    #pragma unroll 1
    for (int tt = 0; tt < T_ / 2; ++tt) {
        step(2 * tt,     xrA);
        step(2 * tt + 1, xrB);
    }

    __syncthreads();   // final full drain before reductions

    // ---- loss partials: per-t reduce + spread atomics (once per block) ----
    if (tid < T_) {
        const int t = tid;
        float num = 0.f;
        for (int i = 0; i < 192; ++i) num += lsum[t * 192 + i];
        float den = 0.f;
        for (int r = 0; r < 16; ++r) den += (float)__popcll(mbits[r * T_ + t]);
        atomicAdd(&ws[t * 8 + (blockIdx.x & 7)], num);
        atomicAdd(&ws[(T_ + t) * 8 + (blockIdx.x & 7)], den);
    }

    // ---- y_h = sigmoid(h(T-1) @ W_out^T + b_out); h(T-1) in Abuf[0] ----
    if (w == 1) {
        float p = 0.f;
        #pragma unroll
        for (int k = 0; k < 16; ++k)
            p += bf2f(Abuf[0][cc * KROW + 72 + 16 * g + k]) * wout[16 * g + k];
        p += __shfl_xor(p, 16, 64);
        p += __shfl_xor(p, 32, 64);
        if (lane < 16) out[1 + batch0 + cc] = rcp_(1.f + exp2_(-(p + wout[64]) * L2E));
    }
}

// loss = (1/T) * sum_t num[t] / (den[t] + 1e-5); slots spread 8-way
__global__ void post_kernel(const float* __restrict__ ws, float* __restrict__ out)
{
    const int t = threadIdx.x;  // 64 threads
    float v = 0.f;
    if (t < T_) {
        float num = 0.f, den = 0.f;
        #pragma unroll
        for (int s = 0; s < 8; ++s) {
            num += ws[t * 8 + s];
            den += ws[(T_ + t) * 8 + s];
        }
        v = num / (den + 1e-5f);
    }
    #pragma unroll
    for (int off = 1; off < 64; off <<= 1) v += __shfl_xor(v, off, 64);
    if (t == 0) out[0] = v * (1.0f / T_);
}

extern "C" void kernel_launch(void* const* d_in, const int* in_sizes, int n_in,
                              void* d_out, int out_size, void* d_ws, size_t ws_size,
                              hipStream_t stream) {
    const float* x_t   = (const float*)d_in[0];
    const float* masks = (const float*)d_in[1];
    const float* W_ih  = (const float*)d_in[6];
    const float* W_hh  = (const float*)d_in[7];
    const float* b_ih  = (const float*)d_in[8];
    const float* b_hh  = (const float*)d_in[9];
    const float* W_reg = (const float*)d_in[10];
    const float* b_reg = (const float*)d_in[11];
    const float* W_out = (const float*)d_in[14];
    const float* b_out = (const float*)d_in[15];
    float* out = (float*)d_out;
    float* ws  = (float*)d_ws;

    hipMemsetAsync(ws, 0, 2 * T_ * 8 * sizeof(float), stream);
    brits_main<<<B_ / 16, 512, 0, stream>>>(x_t, masks, W_ih, W_hh, b_ih, b_hh,
                                            W_reg, b_reg, W_out, b_out, ws, out);
    post_kernel<<<1, 64, 0, stream>>>(ws, out);
}